// Round 9
// baseline (61.042 us; speedup 1.0000x reference)
//
#include <hip/hip_runtime.h>

#define N_    32
#define CIN   128
#define H_    56
#define W_    56
#define HW_   (H_ * W_)
#define COUT  256
#define GROUPS 4
#define CPG   32      // in-channels per group
#define OPG   64      // out-channels per group
#define CDIM  64
#define HP    58      // padded spatial dim (1-px zero halo each side)

#define TH    4               // output rows per block
#define NPIX  (TH * W_)       // 224
#define NT    (NPIX / 16)     // 14 pixel tiles per wave
#define ROWB  (HP * CPG)      // bf16 per padded row = 1856 (3712 B)

// fallback-path tile geometry (R2 kernel)
#define FB_TH   8
#define HALO_R (FB_TH + 2)
#define HALO_C (W_ + 2)
#define XPLANE (HALO_R * HALO_C)

typedef __bf16 bf16x8 __attribute__((ext_vector_type(8)));
typedef __bf16 bf16x2 __attribute__((ext_vector_type(2)));
typedef float  f32x4  __attribute__((ext_vector_type(4)));
typedef unsigned int u32x4 __attribute__((ext_vector_type(4)));

// ---------- merged pre-kernel: xpose (7424 blocks) + ctx (32) + wconv (36) ----------
// xt layout: [n][g][58 padded rows][58 pixels][32 ic] bf16 — LINEAR (no swizzle;
// main kernel reads it from L2 with contiguous 1KB/wave loads, no LDS banking).
__global__ __launch_bounds__(256) void pre_kernel(
    const float* __restrict__ x, const float* __restrict__ c,
    const float* __restrict__ wgt, const float* __restrict__ bias,
    const float* __restrict__ cw,
    __bf16* __restrict__ xt, float* __restrict__ gctx, __bf16* __restrict__ wbf)
{
    const int bid = blockIdx.x;
    const int tid = threadIdx.x;

    if (bid < HP * GROUPS * N_) {                 // ---- xpose ----
        const int hh = bid % HP;
        const int g  = (bid / HP) & (GROUPS - 1);
        const int n  = bid / (HP * GROUPS);
        uint* drow = (uint*)(xt + ((size_t)(n * GROUPS + g) * HP + hh) * ROWB);  // 928 dwords
        const int h = hh - 1;
        if ((unsigned)h >= (unsigned)H_) {        // top/bottom halo row: zeros
            for (int j = tid; j < HP * CPG / 2; j += 256) drow[j] = 0u;
            return;
        }
        __shared__ float t[W_][33];               // [w][ic], pad 33 -> conflict-free
        const float* src = x + ((size_t)(n * CIN + g * CPG) * H_ + h) * W_;
        for (int j = tid; j < CPG * W_; j += 256) {   // coalesced along w
            int ic = j / W_, w = j - ic * W_;
            t[w][ic] = src[(size_t)ic * HW_ + w];
        }
        __syncthreads();
        for (int j = tid; j < HP * CPG / 2; j += 256) {   // 928 dwords, coalesced write
            int pix = j >> 4, icp = j & 15;
            int w = pix - 1;
            uint val = 0u;
            if ((unsigned)w < (unsigned)W_) {
                bf16x2 v;
                v[0] = (__bf16)t[w][icp * 2];
                v[1] = (__bf16)t[w][icp * 2 + 1];
                val = __builtin_bit_cast(unsigned int, v);
            }
            drow[j] = val;                        // linear [pix][ic]
        }
    } else if (bid < HP * GROUPS * N_ + N_) {     // ---- ctx ----
        const int n  = bid - HP * GROUPS * N_;
        const int oc = tid;
        const float* cn  = c  + n * CDIM;
        const float* cwo = cw + oc * CDIM;
        float s = bias[oc];
        #pragma unroll
        for (int d = 0; d < CDIM; ++d) s += cn[d] * cwo[d];
        gctx[n * COUT + oc] = s;
    } else {                                      // ---- wconv: bf16 [g][tap][oct][ocL][8] ----
        int j = (bid - (HP * GROUPS * N_ + N_)) * 256 + tid;
        int e   = j & 7;
        int r   = j >> 3;
        int ocL = r & 63;  r >>= 6;
        int o   = r & 3;   r >>= 2;               // ic octet
        int tap = r % 9;
        int g   = r / 9;
        int ic  = o * 8 + e;
        wbf[j] = (__bf16)wgt[((g * OPG + ocL) * CPG + ic) * 9 + tap];
    }
}

// ---------- main kernel: NO LDS, NO BARRIER — b-frags direct from L2-hot xt ----------
// 1792 blocks x 128 threads (2 waves). Wave = one oc-pair (32 oc) over a 4-row strip.
// Per tile: 1 base address, 9 global_load_dwordx4 with imm offsets (kh*58+kw)*64B
// (all < 8192), each covering a contiguous 1KB per wave. waves_per_eu(4) caps the
// allocator at 128 VGPR so the 72-VGPR pinned a-frag set stays register-resident
// (R6 evidence: default target downgraded to 64 regs and spilled it).
__global__ __attribute__((amdgpu_flat_work_group_size(128, 128), amdgpu_waves_per_eu(4)))
void conv_main(
    const __bf16* __restrict__ xt, const __bf16* __restrict__ wbf,
    const float* __restrict__ gctx, float* __restrict__ out)
{
    const int ht  = blockIdx.x;   // 0..13 (4-row strip)
    const int g   = blockIdx.y;   // 0..3
    const int n   = blockIdx.z;   // 0..31
    const int tid = threadIdx.x;  // 0..127 (2 waves)
    const int h0  = ht * TH;

    const int wv   = tid >> 6;       // 0..1 = oc-pair
    const int lane = tid & 63;
    const int l15  = lane & 15;
    const int kh4  = lane >> 4;      // ic octet / D row group
    const int p2   = wv * 2;         // oc-tile pair base (0 or 2)

    // ---- a-frags from pre-permuted global; PIN in VGPRs so compiler can't sink ----
    u32x4 a[2][9];
    {
        const __bf16* wgb = wbf + (size_t)g * (9 * 4 * OPG * 8);
        #pragma unroll
        for (int i = 0; i < 2; ++i)
            #pragma unroll
            for (int tap = 0; tap < 9; ++tap)
                a[i][tap] = *(const u32x4*)&wgb[(((tap * 4 + kh4) * OPG) + (p2 + i) * 16 + l15) * 8];
    }
    #pragma unroll
    for (int i = 0; i < 2; ++i)
        #pragma unroll
        for (int tap = 0; tap < 9; ++tap)
            asm volatile("" : "+v"(a[i][tap]));

    float ctxv[2][4];
    #pragma unroll
    for (int i = 0; i < 2; ++i)
        #pragma unroll
        for (int r = 0; r < 4; ++r)
            ctxv[i][r] = gctx[n * COUT + g * OPG + (p2 + i) * 16 + kh4 * 4 + r];

    const __bf16* xb = xt + (size_t)(n * GROUPS + g) * (HP * ROWB);
    float* outb = out + ((size_t)n * COUT + g * OPG + p2 * 16 + kh4 * 4) * HW_ + h0 * W_;

    #pragma unroll 1
    for (int t = 0; t < NT; ++t) {
        int p  = t * 16 + l15;           // pixel within strip (B col & D col)
        int pr = p / W_;
        int pc = p - pr * W_;
        // base = padded(h0+pr, pc); taps fold into 13-bit imm offsets
        const __bf16* bb = xb + ((h0 + pr) * HP + pc) * CPG + kh4 * 8;
        f32x4 acc0 = {ctxv[0][0], ctxv[0][1], ctxv[0][2], ctxv[0][3]};  // ctx as C-init
        f32x4 acc1 = {ctxv[1][0], ctxv[1][1], ctxv[1][2], ctxv[1][3]};
        #pragma unroll
        for (int kh = 0; kh < 3; ++kh) {
            #pragma unroll
            for (int kw = 0; kw < 3; ++kw) {
                const bf16x8 b = *(const bf16x8*)&bb[(kh * HP + kw) * CPG];
                acc0 = __builtin_amdgcn_mfma_f32_16x16x32_bf16(
                           __builtin_bit_cast(bf16x8, a[0][kh * 3 + kw]), b, acc0, 0, 0, 0);
                acc1 = __builtin_amdgcn_mfma_f32_16x16x32_bf16(
                           __builtin_bit_cast(bf16x8, a[1][kh * 3 + kw]), b, acc1, 0, 0, 0);
            }
        }
        #pragma unroll
        for (int r = 0; r < 4; ++r)
            outb[(size_t)r * HW_ + p] = acc0[r];
        #pragma unroll
        for (int r = 0; r < 4; ++r)
            outb[(size_t)(16 + r) * HW_ + p] = acc1[r];
    }
}

// ---------- fallback (R2 structure) if workspace can't hold xt ----------
__global__ void ctx_kernel_fb(const float* __restrict__ c, const float* __restrict__ bias,
                              const float* __restrict__ cw, float* __restrict__ gctx) {
    const int n  = blockIdx.x;
    const int oc = threadIdx.x;
    const float* cn  = c  + n * CDIM;
    const float* cwo = cw + oc * CDIM;
    float s = bias[oc];
    #pragma unroll
    for (int d = 0; d < CDIM; ++d) s += cn[d] * cwo[d];
    gctx[n * COUT + oc] = s;
}
__global__ void wconv_kernel_fb(const float* __restrict__ wgt, __bf16* __restrict__ wbf) {
    int j = blockIdx.x * 256 + threadIdx.x;
    int e   = j & 7;
    int r   = j >> 3;
    int ocL = r & 63;  r >>= 6;
    int o   = r & 3;   r >>= 2;
    int tap = r % 9;
    int g   = r / 9;
    int ic  = o * 8 + e;
    wbf[j] = (__bf16)wgt[((g * OPG + ocL) * CPG + ic) * 9 + tap];
}
__global__ __launch_bounds__(512, 4) void ctx_conv_fb(
    const float* __restrict__ x, const __bf16* __restrict__ wbf,
    const float* __restrict__ gctx, float* __restrict__ out)
{
    __shared__ __align__(16) __bf16 x_lds[XPLANE][CPG];
    const int ht  = blockIdx.x;
    const int g   = blockIdx.y;
    const int n   = blockIdx.z;
    const int tid = threadIdx.x;
    const int h0  = ht * FB_TH;
    const int wv   = tid >> 6;
    const int lane = tid & 63;
    const int l15  = lane & 15;
    const int kh4  = lane >> 4;
    const int p2   = (wv & 1) * 2;
    const int pq   = wv >> 1;

    bf16x8 a[2][9];
    {
        const __bf16* wgb = wbf + (size_t)g * (9 * 4 * OPG * 8);
        #pragma unroll
        for (int i = 0; i < 2; ++i)
            #pragma unroll
            for (int tap = 0; tap < 9; ++tap)
                a[i][tap] = *(const bf16x8*)&wgb[(((tap * 4 + kh4) * OPG) + (p2 + i) * 16 + l15) * 8];
    }
    float ctxv[2][4];
    #pragma unroll
    for (int i = 0; i < 2; ++i)
        #pragma unroll
        for (int r = 0; r < 4; ++r)
            ctxv[i][r] = gctx[n * COUT + g * OPG + (p2 + i) * 16 + kh4 * 4 + r];
    {
        const float* xg = x + ((size_t)n * CIN + g * CPG) * HW_;
        for (int j = tid; j < 4 * XPLANE; j += 512) {
            int pix = j >> 2;
            int oct = j & 3;
            int hr = pix / HALO_C;
            int wc = pix - hr * HALO_C;
            int hg  = h0 - 1 + hr;
            int wg2 = wc - 1;
            bool valid = ((unsigned)hg < (unsigned)H_) && ((unsigned)wg2 < (unsigned)W_);
            const float* src = xg + (size_t)(oct * 8) * HW_ + hg * W_ + wg2;
            bf16x8 v;
            #pragma unroll
            for (int e = 0; e < 8; ++e)
                v[e] = (__bf16)(valid ? src[(size_t)e * HW_] : 0.f);
            *(bf16x8*)&x_lds[pix][oct * 8] = v;
        }
    }
    __syncthreads();
    float* outb = out + ((size_t)n * COUT + g * OPG + p2 * 16 + kh4 * 4) * HW_ + h0 * W_;
    #pragma unroll 1
    for (int t = pq * 7; t < pq * 7 + 7; ++t) {
        int p  = t * 16 + l15;
        int pr = p / W_;
        int pc = p - pr * W_;
        f32x4 acc0 = {0.f, 0.f, 0.f, 0.f};
        f32x4 acc1 = {0.f, 0.f, 0.f, 0.f};
        #pragma unroll
        for (int kh = 0; kh < 3; ++kh) {
            #pragma unroll
            for (int kw = 0; kw < 3; ++kw) {
                const bf16x8 b = *(const bf16x8*)&x_lds[(pr + kh) * HALO_C + (pc + kw)][kh4 * 8];
                acc0 = __builtin_amdgcn_mfma_f32_16x16x32_bf16(a[0][kh * 3 + kw], b, acc0, 0, 0, 0);
                acc1 = __builtin_amdgcn_mfma_f32_16x16x32_bf16(a[1][kh * 3 + kw], b, acc1, 0, 0, 0);
            }
        }
        #pragma unroll
        for (int r = 0; r < 4; ++r)
            outb[(size_t)r * HW_ + p] = acc0[r] + ctxv[0][r];
        #pragma unroll
        for (int r = 0; r < 4; ++r)
            outb[(size_t)(16 + r) * HW_ + p] = acc1[r] + ctxv[1][r];
    }
}

extern "C" void kernel_launch(void* const* d_in, const int* in_sizes, int n_in,
                              void* d_out, int out_size, void* d_ws, size_t ws_size,
                              hipStream_t stream) {
    const float* x    = (const float*)d_in[0];
    const float* c    = (const float*)d_in[1];
    const float* wgt  = (const float*)d_in[2];
    const float* bias = (const float*)d_in[3];
    const float* cw   = (const float*)d_in[4];
    float* out = (float*)d_out;

    const size_t XT_BYTES   = (size_t)N_ * GROUPS * HP * HP * CPG * 2;   // 27,557,888
    const size_t GCTX_BYTES = (size_t)N_ * COUT * 4;                     // 32,768
    const size_t WBF_BYTES  = (size_t)COUT * CPG * 9 * 2;                // 147,456
    const size_t NEEDED     = XT_BYTES + GCTX_BYTES + WBF_BYTES;

    if (ws_size >= NEEDED) {
        __bf16* xt   = (__bf16*)d_ws;
        float*  gctx = (float*)((char*)d_ws + XT_BYTES);
        __bf16* wbf  = (__bf16*)((char*)d_ws + XT_BYTES + GCTX_BYTES);

        const int nxpose = HP * GROUPS * N_;                       // 7424
        const int npre   = nxpose + N_ + (COUT * CPG * 9) / 256;   // +32 +36
        pre_kernel<<<dim3(npre), 256, 0, stream>>>(x, c, wgt, bias, cw, xt, gctx, wbf);

        dim3 grid(H_ / TH, GROUPS, N_);   // (14, 4, 32) = 1792 blocks x 128 thr
        conv_main<<<grid, 128, 0, stream>>>(xt, wbf, gctx, out);
    } else {
        float*  gctx = (float*)d_ws;
        __bf16* wbf  = (__bf16*)((char*)d_ws + 32768);
        ctx_kernel_fb<<<dim3(N_), 256, 0, stream>>>(c, bias, cw, gctx);
        wconv_kernel_fb<<<dim3((COUT * CPG * 9) / 256), 256, 0, stream>>>(wgt, wbf);
        dim3 grid(H_ / FB_TH, GROUPS, N_);
        ctx_conv_fb<<<grid, 512, 0, stream>>>(x, wbf, gctx, out);
    }
}

// Round 10
// 50.706 us; speedup vs baseline: 1.2038x; 1.2038x over previous
//
#include <hip/hip_runtime.h>

#define N_    32
#define CIN   128
#define H_    56
#define W_    56
#define HW_   (H_ * W_)
#define COUT  256
#define GROUPS 4
#define CPG   32      // in-channels per group
#define OPG   64      // out-channels per group
#define CDIM  64
#define HP    58      // padded spatial dim (1-px zero halo each side)

#define TH    4               // output rows per block
#define NPIX  (TH * W_)       // 224
#define NT    (NPIX / 16)     // 14 pixel tiles per wave
#define ROWB  (HP * CPG)      // bf16 per padded row = 1856 (3712 B)
#define SROWS 6               // staged padded rows per block
#define CHUNKS 22             // ceil(6*3712/1024) chunks of 1KB
#define LDS_B (CHUNKS * 1024) // 22528 B (includes 256B tail slack, never read)

// fallback-path tile geometry (R2 kernel)
#define FB_TH   8
#define HALO_R (FB_TH + 2)
#define HALO_C (W_ + 2)
#define XPLANE (HALO_R * HALO_C)

typedef __bf16 bf16x8 __attribute__((ext_vector_type(8)));
typedef __bf16 bf16x2 __attribute__((ext_vector_type(2)));
typedef float  f32x4  __attribute__((ext_vector_type(4)));
typedef unsigned int u32x4 __attribute__((ext_vector_type(4)));

__device__ __forceinline__ void gload16(const void* g, void* l) {
    __builtin_amdgcn_global_load_lds((const __attribute__((address_space(1))) void*)g,
                                     (__attribute__((address_space(3))) void*)l, 16, 0, 0);
}

// ---------- merged pre-kernel: xpose (7424) + ctx (32) + wconv (36) ----------
// xt layout: [n][g][58 rows][58 pixels][4 slots][8 ic] bf16; octet o of pixel pix
// stored at slot o ^ ((pix>>1)&3). This swizzle makes the main kernel's b-reads
// 2-way (free) instead of 8-way: b-read phase (16 lanes, stride 64B) hits only 2
// addr classes mod 128 unswizzled; the pix-parity XOR spreads it to 8 classes.
__global__ __launch_bounds__(256) void pre_kernel(
    const float* __restrict__ x, const float* __restrict__ c,
    const float* __restrict__ wgt, const float* __restrict__ bias,
    const float* __restrict__ cw,
    __bf16* __restrict__ xt, float* __restrict__ gctx, __bf16* __restrict__ wbf)
{
    const int bid = blockIdx.x;
    const int tid = threadIdx.x;

    if (bid < HP * GROUPS * N_) {                 // ---- xpose ----
        const int hh = bid % HP;
        const int g  = (bid / HP) & (GROUPS - 1);
        const int n  = bid / (HP * GROUPS);
        uint* drow = (uint*)(xt + ((size_t)(n * GROUPS + g) * HP + hh) * ROWB);  // 928 dwords
        const int h = hh - 1;
        if ((unsigned)h >= (unsigned)H_) {        // top/bottom halo row: zeros
            for (int j = tid; j < HP * CPG / 2; j += 256) drow[j] = 0u;
            return;
        }
        __shared__ float t[W_][33];               // [w][ic], pad 33 -> conflict-free
        const float* src = x + ((size_t)(n * CIN + g * CPG) * H_ + h) * W_;
        for (int j = tid; j < CPG * W_; j += 256) {   // coalesced along w
            int ic = j / W_, w = j - ic * W_;
            t[w][ic] = src[(size_t)ic * HW_ + w];
        }
        __syncthreads();
        for (int j = tid; j < HP * CPG / 2; j += 256) {   // 928 dwords, coalesced
            int pix = j >> 4, icp = j & 15;
            int w = pix - 1;
            uint val = 0u;
            if ((unsigned)w < (unsigned)W_) {
                bf16x2 v;
                v[0] = (__bf16)t[w][icp * 2];
                v[1] = (__bf16)t[w][icp * 2 + 1];
                val = __builtin_bit_cast(unsigned int, v);
            }
            int o = icp >> 2, d = icp & 3;
            int slot = o ^ ((pix >> 1) & 3);
            drow[(pix << 4) + (slot << 2) + d] = val;
        }
    } else if (bid < HP * GROUPS * N_ + N_) {     // ---- ctx ----
        const int n  = bid - HP * GROUPS * N_;
        const int oc = tid;
        const float* cn  = c  + n * CDIM;
        const float* cwo = cw + oc * CDIM;
        float s = bias[oc];
        #pragma unroll
        for (int d = 0; d < CDIM; ++d) s += cn[d] * cwo[d];
        gctx[n * COUT + oc] = s;
    } else {                                      // ---- wconv: bf16 [g][tap][oct][ocL][8] ----
        int j = (bid - (HP * GROUPS * N_ + N_)) * 256 + tid;
        int e   = j & 7;
        int r   = j >> 3;
        int ocL = r & 63;  r >>= 6;
        int o   = r & 3;   r >>= 2;               // ic octet
        int tap = r % 9;
        int g   = r / 9;
        int ic  = o * 8 + e;
        wbf[j] = (__bf16)wgt[((g * OPG + ocL) * CPG + ic) * 9 + tap];
    }
}

// ---------- main kernel: fine-grained 2-wave blocks, gload_lds-staged LDS ----------
// 1792 blocks (= 7 exact generations/CU) x 128 thr. Per block: stage 6 padded rows
// (22.3KB, 22 async chunks), one 2-wave barrier, then each wave computes its
// 32-oc pair over all 14 pixel tiles from LDS. 7 blocks/CU resident (LDS-capped).
__global__ __attribute__((amdgpu_flat_work_group_size(128, 128), amdgpu_waves_per_eu(4, 4)))
void conv_main(
    const __bf16* __restrict__ xt, const __bf16* __restrict__ wbf,
    const float* __restrict__ gctx, float* __restrict__ out)
{
    __shared__ __align__(16) __bf16 x_lds[LDS_B / 2];   // 22528 B

    const int ht  = blockIdx.x;   // 0..13 (4-row strip)
    const int g   = blockIdx.y;   // 0..3
    const int n   = blockIdx.z;   // 0..31
    const int tid = threadIdx.x;  // 0..127 (2 waves)
    const int h0  = ht * TH;

    const int wv   = tid >> 6;       // 0..1 = oc-pair
    const int lane = tid & 63;
    const int l15  = lane & 15;
    const int kh4  = lane >> 4;      // ic octet / D row group
    const int p2   = wv * 2;         // oc-tile pair base (0 or 2)

    // ---- stage 6 padded rows h0..h0+5 FIRST (latency overlaps loads below) ----
    {
        const char* sbase = (const char*)(xt + ((size_t)(n * GROUPS + g) * HP + h0) * ROWB);
        char* lbase = (char*)&x_lds[0];
        #pragma unroll
        for (int ch = 0; ch < CHUNKS / 2; ++ch) {           // 11 insts per wave
            int c2 = ch * 2 + wv;                           // wave-uniform dest base
            gload16(sbase + c2 * 1024 + lane * 16, lbase + c2 * 1024);
        }
        // (last chunk's 256B tail slack may read past this strip — stays inside
        //  d_ws [xt|gctx|wbf] and is never consumed from LDS)
    }

    // ---- a-frags from pre-permuted global; PIN in VGPRs so compiler can't sink ----
    u32x4 a[2][9];
    {
        const __bf16* wgb = wbf + (size_t)g * (9 * 4 * OPG * 8);
        #pragma unroll
        for (int i = 0; i < 2; ++i)
            #pragma unroll
            for (int tap = 0; tap < 9; ++tap)
                a[i][tap] = *(const u32x4*)&wgb[(((tap * 4 + kh4) * OPG) + (p2 + i) * 16 + l15) * 8];
    }
    #pragma unroll
    for (int i = 0; i < 2; ++i)
        #pragma unroll
        for (int tap = 0; tap < 9; ++tap)
            asm volatile("" : "+v"(a[i][tap]));

    float ctxv[2][4];
    #pragma unroll
    for (int i = 0; i < 2; ++i)
        #pragma unroll
        for (int r = 0; r < 4; ++r)
            ctxv[i][r] = gctx[n * COUT + g * OPG + (p2 + i) * 16 + kh4 * 4 + r];

    __syncthreads();   // 2-wave barrier (drains the 22 staged chunks)

    float* outb = out + ((size_t)n * COUT + g * OPG + p2 * 16 + kh4 * 4) * HW_ + h0 * W_;

    #pragma unroll 1
    for (int t = 0; t < NT; ++t) {
        int p  = t * 16 + l15;           // pixel within strip (B col & D col)
        int pr = p / W_;
        int pc = p - pr * W_;
        f32x4 acc0 = {ctxv[0][0], ctxv[0][1], ctxv[0][2], ctxv[0][3]};  // ctx as C-init
        f32x4 acc1 = {ctxv[1][0], ctxv[1][1], ctxv[1][2], ctxv[1][3]};
        #pragma unroll
        for (int kh = 0; kh < 3; ++kh) {
            #pragma unroll
            for (int kw = 0; kw < 3; ++kw) {
                int pix = pc + kw;
                int idx = (pr + kh) * ROWB + pix * CPG + ((kh4 ^ ((pix >> 1) & 3)) << 3);
                const bf16x8 b = *(const bf16x8*)&x_lds[idx];
                acc0 = __builtin_amdgcn_mfma_f32_16x16x32_bf16(
                           __builtin_bit_cast(bf16x8, a[0][kh * 3 + kw]), b, acc0, 0, 0, 0);
                acc1 = __builtin_amdgcn_mfma_f32_16x16x32_bf16(
                           __builtin_bit_cast(bf16x8, a[1][kh * 3 + kw]), b, acc1, 0, 0, 0);
            }
        }
        #pragma unroll
        for (int r = 0; r < 4; ++r)
            outb[(size_t)r * HW_ + p] = acc0[r];
        #pragma unroll
        for (int r = 0; r < 4; ++r)
            outb[(size_t)(16 + r) * HW_ + p] = acc1[r];
    }
}

// ---------- fallback (R2 structure) if workspace can't hold xt ----------
__global__ void ctx_kernel_fb(const float* __restrict__ c, const float* __restrict__ bias,
                              const float* __restrict__ cw, float* __restrict__ gctx) {
    const int n  = blockIdx.x;
    const int oc = threadIdx.x;
    const float* cn  = c  + n * CDIM;
    const float* cwo = cw + oc * CDIM;
    float s = bias[oc];
    #pragma unroll
    for (int d = 0; d < CDIM; ++d) s += cn[d] * cwo[d];
    gctx[n * COUT + oc] = s;
}
__global__ void wconv_kernel_fb(const float* __restrict__ wgt, __bf16* __restrict__ wbf) {
    int j = blockIdx.x * 256 + threadIdx.x;
    int e   = j & 7;
    int r   = j >> 3;
    int ocL = r & 63;  r >>= 6;
    int o   = r & 3;   r >>= 2;
    int tap = r % 9;
    int g   = r / 9;
    int ic  = o * 8 + e;
    wbf[j] = (__bf16)wgt[((g * OPG + ocL) * CPG + ic) * 9 + tap];
}
__global__ __launch_bounds__(512, 4) void ctx_conv_fb(
    const float* __restrict__ x, const __bf16* __restrict__ wbf,
    const float* __restrict__ gctx, float* __restrict__ out)
{
    __shared__ __align__(16) __bf16 x_lds[XPLANE][CPG];
    const int ht  = blockIdx.x;
    const int g   = blockIdx.y;
    const int n   = blockIdx.z;
    const int tid = threadIdx.x;
    const int h0  = ht * FB_TH;
    const int wv   = tid >> 6;
    const int lane = tid & 63;
    const int l15  = lane & 15;
    const int kh4  = lane >> 4;
    const int p2   = (wv & 1) * 2;
    const int pq   = wv >> 1;

    bf16x8 a[2][9];
    {
        const __bf16* wgb = wbf + (size_t)g * (9 * 4 * OPG * 8);
        #pragma unroll
        for (int i = 0; i < 2; ++i)
            #pragma unroll
            for (int tap = 0; tap < 9; ++tap)
                a[i][tap] = *(const bf16x8*)&wgb[(((tap * 4 + kh4) * OPG) + (p2 + i) * 16 + l15) * 8];
    }
    float ctxv[2][4];
    #pragma unroll
    for (int i = 0; i < 2; ++i)
        #pragma unroll
        for (int r = 0; r < 4; ++r)
            ctxv[i][r] = gctx[n * COUT + g * OPG + (p2 + i) * 16 + kh4 * 4 + r];
    {
        const float* xg = x + ((size_t)n * CIN + g * CPG) * HW_;
        for (int j = tid; j < 4 * XPLANE; j += 512) {
            int pix = j >> 2;
            int oct = j & 3;
            int hr = pix / HALO_C;
            int wc = pix - hr * HALO_C;
            int hg  = h0 - 1 + hr;
            int wg2 = wc - 1;
            bool valid = ((unsigned)hg < (unsigned)H_) && ((unsigned)wg2 < (unsigned)W_);
            const float* src = xg + (size_t)(oct * 8) * HW_ + hg * W_ + wg2;
            bf16x8 v;
            #pragma unroll
            for (int e = 0; e < 8; ++e)
                v[e] = (__bf16)(valid ? src[(size_t)e * HW_] : 0.f);
            *(bf16x8*)&x_lds[pix][oct * 8] = v;
        }
    }
    __syncthreads();
    float* outb = out + ((size_t)n * COUT + g * OPG + p2 * 16 + kh4 * 4) * HW_ + h0 * W_;
    #pragma unroll 1
    for (int t = pq * 7; t < pq * 7 + 7; ++t) {
        int p  = t * 16 + l15;
        int pr = p / W_;
        int pc = p - pr * W_;
        f32x4 acc0 = {0.f, 0.f, 0.f, 0.f};
        f32x4 acc1 = {0.f, 0.f, 0.f, 0.f};
        #pragma unroll
        for (int kh = 0; kh < 3; ++kh) {
            #pragma unroll
            for (int kw = 0; kw < 3; ++kw) {
                const bf16x8 b = *(const bf16x8*)&x_lds[(pr + kh) * HALO_C + (pc + kw)][kh4 * 8];
                acc0 = __builtin_amdgcn_mfma_f32_16x16x32_bf16(a[0][kh * 3 + kw], b, acc0, 0, 0, 0);
                acc1 = __builtin_amdgcn_mfma_f32_16x16x32_bf16(a[1][kh * 3 + kw], b, acc1, 0, 0, 0);
            }
        }
        #pragma unroll
        for (int r = 0; r < 4; ++r)
            outb[(size_t)r * HW_ + p] = acc0[r] + ctxv[0][r];
        #pragma unroll
        for (int r = 0; r < 4; ++r)
            outb[(size_t)(16 + r) * HW_ + p] = acc1[r] + ctxv[1][r];
    }
}

extern "C" void kernel_launch(void* const* d_in, const int* in_sizes, int n_in,
                              void* d_out, int out_size, void* d_ws, size_t ws_size,
                              hipStream_t stream) {
    const float* x    = (const float*)d_in[0];
    const float* c    = (const float*)d_in[1];
    const float* wgt  = (const float*)d_in[2];
    const float* bias = (const float*)d_in[3];
    const float* cw   = (const float*)d_in[4];
    float* out = (float*)d_out;

    const size_t XT_BYTES   = (size_t)N_ * GROUPS * HP * HP * CPG * 2;   // 27,557,888
    const size_t GCTX_BYTES = (size_t)N_ * COUT * 4;                     // 32,768
    const size_t WBF_BYTES  = (size_t)COUT * CPG * 9 * 2;                // 147,456
    const size_t NEEDED     = XT_BYTES + GCTX_BYTES + WBF_BYTES;

    if (ws_size >= NEEDED) {
        __bf16* xt   = (__bf16*)d_ws;
        float*  gctx = (float*)((char*)d_ws + XT_BYTES);
        __bf16* wbf  = (__bf16*)((char*)d_ws + XT_BYTES + GCTX_BYTES);

        const int nxpose = HP * GROUPS * N_;                       // 7424
        const int npre   = nxpose + N_ + (COUT * CPG * 9) / 256;   // +32 +36
        pre_kernel<<<dim3(npre), 256, 0, stream>>>(x, c, wgt, bias, cw, xt, gctx, wbf);

        dim3 grid(H_ / TH, GROUPS, N_);   // (14, 4, 32) = 1792 blocks x 128 thr
        conv_main<<<grid, 128, 0, stream>>>(xt, wbf, gctx, out);
    } else {
        float*  gctx = (float*)d_ws;
        __bf16* wbf  = (__bf16*)((char*)d_ws + 32768);
        ctx_kernel_fb<<<dim3(N_), 256, 0, stream>>>(c, bias, cw, gctx);
        wconv_kernel_fb<<<dim3((COUT * CPG * 9) / 256), 256, 0, stream>>>(wgt, wbf);
        dim3 grid(H_ / FB_TH, GROUPS, N_);
        ctx_conv_fb<<<grid, 512, 0, stream>>>(x, wbf, gctx, out);
    }
}

// Round 11
// 49.907 us; speedup vs baseline: 1.2231x; 1.0160x over previous
//
#include <hip/hip_runtime.h>

#define N_    32
#define CIN   128
#define H_    56
#define W_    56
#define HW_   (H_ * W_)
#define COUT  256
#define GROUPS 4
#define CPG   32      // in-channels per group
#define OPG   64      // out-channels per group
#define CDIM  64
#define HP    58      // padded spatial dim (1-px zero halo each side)

#define TH    8               // output rows per block
#define NPIX  (TH * W_)       // 448
#define NT    (NPIX / 16)     // 28 pixel tiles (14 per wave-half)

#define ROWB  (HP * CPG)      // bf16 per padded row = 1856 (3712 B)
#define STRIP_CHUNKS 37       // ceil(10*3712 / 1024)

// fallback-path tile geometry (R2 kernel)
#define FB_TH   8
#define HALO_R (FB_TH + 2)
#define HALO_C (W_ + 2)
#define XPLANE (HALO_R * HALO_C)

typedef __bf16 bf16x8 __attribute__((ext_vector_type(8)));
typedef __bf16 bf16x2 __attribute__((ext_vector_type(2)));
typedef float  f32x4  __attribute__((ext_vector_type(4)));
typedef unsigned int u32x4 __attribute__((ext_vector_type(4)));

__device__ __forceinline__ void gload16(const void* g, void* l) {
    __builtin_amdgcn_global_load_lds((const __attribute__((address_space(1))) void*)g,
                                     (__attribute__((address_space(3))) void*)l, 16, 0, 0);
}

// ---------- merged pre-kernel: xpose (7424) + ctx (32) + wconv (36) ----------
// xt layout: [n][g][58 rows][58 pixels][4 slots][8 ic] bf16; octet o of pixel pix
// stored at slot o ^ ((pix>>1)&3)  (LDS bank swizzle; read applies the same XOR).
__global__ __launch_bounds__(256) void pre_kernel(
    const float* __restrict__ x, const float* __restrict__ c,
    const float* __restrict__ wgt, const float* __restrict__ bias,
    const float* __restrict__ cw,
    __bf16* __restrict__ xt, float* __restrict__ gctx, __bf16* __restrict__ wbf)
{
    const int bid = blockIdx.x;
    const int tid = threadIdx.x;

    if (bid < HP * GROUPS * N_) {                 // ---- xpose ----
        const int hh = bid % HP;
        const int g  = (bid / HP) & (GROUPS - 1);
        const int n  = bid / (HP * GROUPS);
        uint* drow = (uint*)(xt + ((size_t)(n * GROUPS + g) * HP + hh) * ROWB);  // 928 dwords
        const int h = hh - 1;
        if ((unsigned)h >= (unsigned)H_) {        // top/bottom halo row: zeros
            for (int j = tid; j < HP * CPG / 2; j += 256) drow[j] = 0u;
            return;
        }
        __shared__ float t[W_][33];               // [w][ic], pad 33 -> conflict-free
        const float* src = x + ((size_t)(n * CIN + g * CPG) * H_ + h) * W_;
        for (int j = tid; j < CPG * W_; j += 256) {   // coalesced along w
            int ic = j / W_, w = j - ic * W_;
            t[w][ic] = src[(size_t)ic * HW_ + w];
        }
        __syncthreads();
        for (int j = tid; j < HP * CPG / 2; j += 256) {   // 928 dwords, coalesced
            int pix = j >> 4, icp = j & 15;
            int w = pix - 1;
            uint val = 0u;
            if ((unsigned)w < (unsigned)W_) {
                bf16x2 v;
                v[0] = (__bf16)t[w][icp * 2];
                v[1] = (__bf16)t[w][icp * 2 + 1];
                val = __builtin_bit_cast(unsigned int, v);
            }
            int o = icp >> 2, d = icp & 3;
            int slot = o ^ ((pix >> 1) & 3);
            drow[(pix << 4) + (slot << 2) + d] = val;
        }
    } else if (bid < HP * GROUPS * N_ + N_) {     // ---- ctx ----
        const int n  = bid - HP * GROUPS * N_;
        const int oc = tid;
        const float* cn  = c  + n * CDIM;
        const float* cwo = cw + oc * CDIM;
        float s = bias[oc];
        #pragma unroll
        for (int d = 0; d < CDIM; ++d) s += cn[d] * cwo[d];
        gctx[n * COUT + oc] = s;
    } else {                                      // ---- wconv: bf16 [g][tap][oct][ocL][8] ----
        int j = (bid - (HP * GROUPS * N_ + N_)) * 256 + tid;
        int e   = j & 7;
        int r   = j >> 3;
        int ocL = r & 63;  r >>= 6;
        int o   = r & 3;   r >>= 2;               // ic octet
        int tap = r % 9;
        int g   = r / 9;
        int ic  = o * 8 + e;
        wbf[j] = (__bf16)wgt[((g * OPG + ocL) * CPG + ic) * 9 + tap];
    }
}

// ---------- main kernel: R4 structure + OPERAND-SWAPPED MFMA ----------
// mfma(x_frag, w_frag, acc): A/B fragment lane maps are identical, so swapping
// args transposes D for free: lane = one oc (l15), regs = 4 CONSECUTIVE pixels
// (kh4*4+r). Epilogue = 1 float4 store per oc-tile per pixel-tile (28 dwordx4
// per wave instead of 112 scalar dwords scattered across oc rows).
__global__ __launch_bounds__(256, 4) void conv_main(
    const __bf16* __restrict__ xt, const __bf16* __restrict__ wbf,
    const float* __restrict__ gctx, float* __restrict__ out)
{
    __shared__ __align__(16) __bf16 x_lds[(STRIP_CHUNKS * 1024) / 2];   // 37888 B

    const int ht  = blockIdx.x;   // 0..6  (8-row strip)
    const int g   = blockIdx.y;   // 0..3
    const int n   = blockIdx.z;   // 0..31
    const int tid = threadIdx.x;  // 0..255 (4 waves)
    const int h0  = ht * TH;

    const int wv   = tid >> 6;       // 0..3
    const int lane = tid & 63;
    const int l15  = lane & 15;
    const int kh4  = lane >> 4;      // ic octet / D pixel-quad group
    const int p2   = (wv & 1) * 2;   // oc-tile pair base (0 or 2)
    const int ph   = wv >> 1;        // pixel half (14 tiles each)

    // ---- stage strip rows h0..h0+9 FIRST (latency overlaps loads below) ----
    {
        const char* sbase = (const char*)(xt + ((size_t)(n * GROUPS + g) * HP + h0) * ROWB);
        char* lbase = (char*)&x_lds[0];
        for (int ch = wv; ch < STRIP_CHUNKS; ch += 4)     // wave-uniform dest base
            gload16(sbase + ch * 1024 + lane * 16, lbase + ch * 1024);
        // (chunk 36 copies 768B of tail slack; stays inside d_ws, never read)
    }

    // ---- w-frags from pre-permuted global; PIN in VGPRs so compiler can't sink ----
    u32x4 a[2][9];
    {
        const __bf16* wgb = wbf + (size_t)g * (9 * 4 * OPG * 8);
        #pragma unroll
        for (int i = 0; i < 2; ++i)
            #pragma unroll
            for (int tap = 0; tap < 9; ++tap)
                a[i][tap] = *(const u32x4*)&wgb[(((tap * 4 + kh4) * OPG) + (p2 + i) * 16 + l15) * 8];
    }
    #pragma unroll
    for (int i = 0; i < 2; ++i)
        #pragma unroll
        for (int tap = 0; tap < 9; ++tap)
            asm volatile("" : "+v"(a[i][tap]));

    // ctx for this lane's oc (one per oc-tile) — coalesced 64B loads
    float ctxv[2];
    #pragma unroll
    for (int i = 0; i < 2; ++i)
        ctxv[i] = gctx[n * COUT + g * OPG + (p2 + i) * 16 + l15];

    __syncthreads();

    // lane's output rows: oc = g*OPG + (p2+i)*16 + l15
    float* outb0 = out + ((size_t)n * COUT + g * OPG + p2 * 16 + l15) * HW_ + h0 * W_;
    float* outb1 = outb0 + (size_t)16 * HW_;

    #pragma unroll 1
    for (int t = ph * 14; t < ph * 14 + 14; ++t) {
        int p  = t * 16 + l15;           // A-row pixel for LDS read
        int pr = p / W_;
        int pc = p - pr * W_;
        f32x4 acc0 = {ctxv[0], ctxv[0], ctxv[0], ctxv[0]};   // ctx as C-init (one oc, 4 px)
        f32x4 acc1 = {ctxv[1], ctxv[1], ctxv[1], ctxv[1]};
        #pragma unroll
        for (int kh = 0; kh < 3; ++kh) {
            #pragma unroll
            for (int kw = 0; kw < 3; ++kw) {
                int pix = pc + kw;
                int idx = (pr + kh) * ROWB + pix * CPG + ((kh4 ^ ((pix >> 1) & 3)) << 3);
                const bf16x8 b = *(const bf16x8*)&x_lds[idx];
                // swapped operands: D[m=pixel][n=oc]
                acc0 = __builtin_amdgcn_mfma_f32_16x16x32_bf16(
                           b, __builtin_bit_cast(bf16x8, a[0][kh * 3 + kw]), acc0, 0, 0, 0);
                acc1 = __builtin_amdgcn_mfma_f32_16x16x32_bf16(
                           b, __builtin_bit_cast(bf16x8, a[1][kh * 3 + kw]), acc1, 0, 0, 0);
            }
        }
        // lane writes 4 consecutive pixels (p0..p0+3, same out row; 56%4==0 so no
        // row straddle; 16B aligned) for its oc in each oc-tile
        int p0 = t * 16 + kh4 * 4;
        *(f32x4*)&outb0[p0] = acc0;
        *(f32x4*)&outb1[p0] = acc1;
    }
}

// ---------- fallback (R2 structure) if workspace can't hold xt ----------
__global__ void ctx_kernel_fb(const float* __restrict__ c, const float* __restrict__ bias,
                              const float* __restrict__ cw, float* __restrict__ gctx) {
    const int n  = blockIdx.x;
    const int oc = threadIdx.x;
    const float* cn  = c  + n * CDIM;
    const float* cwo = cw + oc * CDIM;
    float s = bias[oc];
    #pragma unroll
    for (int d = 0; d < CDIM; ++d) s += cn[d] * cwo[d];
    gctx[n * COUT + oc] = s;
}
__global__ void wconv_kernel_fb(const float* __restrict__ wgt, __bf16* __restrict__ wbf) {
    int j = blockIdx.x * 256 + threadIdx.x;
    int e   = j & 7;
    int r   = j >> 3;
    int ocL = r & 63;  r >>= 6;
    int o   = r & 3;   r >>= 2;
    int tap = r % 9;
    int g   = r / 9;
    int ic  = o * 8 + e;
    wbf[j] = (__bf16)wgt[((g * OPG + ocL) * CPG + ic) * 9 + tap];
}
__global__ __launch_bounds__(512, 4) void ctx_conv_fb(
    const float* __restrict__ x, const __bf16* __restrict__ wbf,
    const float* __restrict__ gctx, float* __restrict__ out)
{
    __shared__ __align__(16) __bf16 x_lds[XPLANE][CPG];
    const int ht  = blockIdx.x;
    const int g   = blockIdx.y;
    const int n   = blockIdx.z;
    const int tid = threadIdx.x;
    const int h0  = ht * FB_TH;
    const int wv   = tid >> 6;
    const int lane = tid & 63;
    const int l15  = lane & 15;
    const int kh4  = lane >> 4;
    const int p2   = (wv & 1) * 2;
    const int pq   = wv >> 1;

    bf16x8 a[2][9];
    {
        const __bf16* wgb = wbf + (size_t)g * (9 * 4 * OPG * 8);
        #pragma unroll
        for (int i = 0; i < 2; ++i)
            #pragma unroll
            for (int tap = 0; tap < 9; ++tap)
                a[i][tap] = *(const bf16x8*)&wgb[(((tap * 4 + kh4) * OPG) + (p2 + i) * 16 + l15) * 8];
    }
    float ctxv[2][4];
    #pragma unroll
    for (int i = 0; i < 2; ++i)
        #pragma unroll
        for (int r = 0; r < 4; ++r)
            ctxv[i][r] = gctx[n * COUT + g * OPG + (p2 + i) * 16 + kh4 * 4 + r];
    {
        const float* xg = x + ((size_t)n * CIN + g * CPG) * HW_;
        for (int j = tid; j < 4 * XPLANE; j += 512) {
            int pix = j >> 2;
            int oct = j & 3;
            int hr = pix / HALO_C;
            int wc = pix - hr * HALO_C;
            int hg  = h0 - 1 + hr;
            int wg2 = wc - 1;
            bool valid = ((unsigned)hg < (unsigned)H_) && ((unsigned)wg2 < (unsigned)W_);
            const float* src = xg + (size_t)(oct * 8) * HW_ + hg * W_ + wg2;
            bf16x8 v;
            #pragma unroll
            for (int e = 0; e < 8; ++e)
                v[e] = (__bf16)(valid ? src[(size_t)e * HW_] : 0.f);
            *(bf16x8*)&x_lds[pix][oct * 8] = v;
        }
    }
    __syncthreads();
    float* outb = out + ((size_t)n * COUT + g * OPG + p2 * 16 + kh4 * 4) * HW_ + h0 * W_;
    #pragma unroll 1
    for (int t = pq * 7; t < pq * 7 + 7; ++t) {
        int p  = t * 16 + l15;
        int pr = p / W_;
        int pc = p - pr * W_;
        f32x4 acc0 = {0.f, 0.f, 0.f, 0.f};
        f32x4 acc1 = {0.f, 0.f, 0.f, 0.f};
        #pragma unroll
        for (int kh = 0; kh < 3; ++kh) {
            #pragma unroll
            for (int kw = 0; kw < 3; ++kw) {
                const bf16x8 b = *(const bf16x8*)&x_lds[(pr + kh) * HALO_C + (pc + kw)][kh4 * 8];
                acc0 = __builtin_amdgcn_mfma_f32_16x16x32_bf16(a[0][kh * 3 + kw], b, acc0, 0, 0, 0);
                acc1 = __builtin_amdgcn_mfma_f32_16x16x32_bf16(a[1][kh * 3 + kw], b, acc1, 0, 0, 0);
            }
        }
        #pragma unroll
        for (int r = 0; r < 4; ++r)
            outb[(size_t)r * HW_ + p] = acc0[r] + ctxv[0][r];
        #pragma unroll
        for (int r = 0; r < 4; ++r)
            outb[(size_t)(16 + r) * HW_ + p] = acc1[r] + ctxv[1][r];
    }
}

extern "C" void kernel_launch(void* const* d_in, const int* in_sizes, int n_in,
                              void* d_out, int out_size, void* d_ws, size_t ws_size,
                              hipStream_t stream) {
    const float* x    = (const float*)d_in[0];
    const float* c    = (const float*)d_in[1];
    const float* wgt  = (const float*)d_in[2];
    const float* bias = (const float*)d_in[3];
    const float* cw   = (const float*)d_in[4];
    float* out = (float*)d_out;

    const size_t XT_BYTES   = (size_t)N_ * GROUPS * HP * HP * CPG * 2;   // 27,557,888
    const size_t GCTX_BYTES = (size_t)N_ * COUT * 4;                     // 32,768
    const size_t WBF_BYTES  = (size_t)COUT * CPG * 9 * 2;                // 147,456
    const size_t NEEDED     = XT_BYTES + GCTX_BYTES + WBF_BYTES;

    if (ws_size >= NEEDED) {
        __bf16* xt   = (__bf16*)d_ws;
        float*  gctx = (float*)((char*)d_ws + XT_BYTES);
        __bf16* wbf  = (__bf16*)((char*)d_ws + XT_BYTES + GCTX_BYTES);

        const int nxpose = HP * GROUPS * N_;                       // 7424
        const int npre   = nxpose + N_ + (COUT * CPG * 9) / 256;   // +32 +36
        pre_kernel<<<dim3(npre), 256, 0, stream>>>(x, c, wgt, bias, cw, xt, gctx, wbf);

        dim3 grid(H_ / TH, GROUPS, N_);   // (7, 4, 32) = 896 blocks x 256 thr
        conv_main<<<grid, 256, 0, stream>>>(xt, wbf, gctx, out);
    } else {
        float*  gctx = (float*)d_ws;
        __bf16* wbf  = (__bf16*)((char*)d_ws + 32768);
        ctx_kernel_fb<<<dim3(N_), 256, 0, stream>>>(c, bias, cw, gctx);
        wconv_kernel_fb<<<dim3((COUT * CPG * 9) / 256), 256, 0, stream>>>(wgt, wbf);
        dim3 grid(H_ / FB_TH, GROUPS, N_);
        ctx_conv_fb<<<grid, 512, 0, stream>>>(x, wbf, gctx, out);
    }
}